// Round 1
// baseline (133.588 us; speedup 1.0000x reference)
//
#include <hip/hip_runtime.h>
#include <cstdint>
#include <cstddef>

#define NH 8
#define DH 64
#define DM 512
#define CTX 64
#define BB 2
#define QL 2048
#define TT (QL + CTX - 1)   // 2111
#define HDIM 512
#define KVN 1024
#define KD 512              // K for all GEMMs

typedef unsigned short u16;
typedef __attribute__((ext_vector_type(8))) short bf16x8;   // 8 bf16 = 4 VGPRs
typedef __attribute__((ext_vector_type(4))) float f32x4;

__device__ __forceinline__ u16 f2bf(float f) {      // RNE float->bf16
    uint32_t u = __float_as_uint(f);
    u += 0x7FFF + ((u >> 16) & 1);
    return (u16)(u >> 16);
}
__device__ __forceinline__ float bf2f(u16 u) {
    return __uint_as_float((uint32_t)u << 16);
}

#define GLLDS(g, l) __builtin_amdgcn_global_load_lds( \
    (const __attribute__((address_space(1))) void*)(g), \
    (__attribute__((address_space(3))) void*)(l), 16, 0, 0)

// ---------------------------------------------------------------------------
// Fused prep: cast x,r -> bf16; transpose+cast Wkv,Wq,Wr,Wo; pad mask.
// ---------------------------------------------------------------------------
__global__ __launch_bounds__(256) void prep_kernel(
    const float* __restrict__ x, const float* __restrict__ r,
    const float* __restrict__ Wkv, const float* __restrict__ Wq,
    const float* __restrict__ Wr, const float* __restrict__ Wo,
    u16* __restrict__ xb, u16* __restrict__ rb, u16* __restrict__ WkvqT,
    u16* __restrict__ WrT, u16* __restrict__ WoT, float* __restrict__ maskv)
{
    __shared__ float tile[64][65];
    __shared__ int anyflag;
    int bid = blockIdx.x;
    const int tid = threadIdx.x;

    if (bid < 2111) {                           // x cast
        int i = bid * 256 + tid;
        float4 v = ((const float4*)x)[i];
        ushort4 o; o.x = f2bf(v.x); o.y = f2bf(v.y); o.z = f2bf(v.z); o.w = f2bf(v.w);
        ((ushort4*)xb)[i] = o;
        return;
    }
    bid -= 2111;
    if (bid < 32) {                             // r cast
        int i = bid * 256 + tid;
        float4 v = ((const float4*)r)[i];
        ushort4 o; o.x = f2bf(v.x); o.y = f2bf(v.y); o.z = f2bf(v.z); o.w = f2bf(v.w);
        ((ushort4*)rb)[i] = o;
        return;
    }
    bid -= 32;
    if (bid >= 320) {                           // pad mask
        int idx = bid - 320;
        int t = idx >> 1, b = idx & 1;
        const float* row = x + (size_t)(b * TT + t) * DM;
        bool nz = (row[tid] != 0.f) || (row[tid + 256] != 0.f);
        if (tid == 0) anyflag = 0;
        __syncthreads();
        unsigned long long bal = __ballot(nz);
        if ((tid & 63) == 0 && bal) atomicOr(&anyflag, 1);
        __syncthreads();
        if (tid == 0) maskv[b * 64 + t] = anyflag ? 0.f : -1e30f;
        return;
    }
    // weight transposes
    const float* W; u16* WT; int N; int tidx;
    if (bid < 128)      { W = Wkv; WT = WkvqT;                    N = 1024; tidx = bid; }
    else if (bid < 192) { W = Wq;  WT = WkvqT + (size_t)1024*512; N = 512;  tidx = bid - 128; }
    else if (bid < 256) { W = Wr;  WT = WrT;                      N = 512;  tidx = bid - 192; }
    else                { W = Wo;  WT = WoT;                      N = 512;  tidx = bid - 256; }
    const int tpr = N / 64;
    const int kb = (tidx / tpr) * 64, nb = (tidx % tpr) * 64;
    const int c4 = (tid & 15) * 4;
    for (int kk = tid >> 4; kk < 64; kk += 16) {
        float4 v = *(const float4*)&W[(size_t)(kb + kk) * N + nb + c4];
        tile[kk][c4 + 0] = v.x; tile[kk][c4 + 1] = v.y;
        tile[kk][c4 + 2] = v.z; tile[kk][c4 + 3] = v.w;
    }
    __syncthreads();
    for (int nn = tid >> 4; nn < 64; nn += 16) {
        ushort4 o;
        o.x = f2bf(tile[c4 + 0][nn]); o.y = f2bf(tile[c4 + 1][nn]);
        o.z = f2bf(tile[c4 + 2][nn]); o.w = f2bf(tile[c4 + 3][nn]);
        *(ushort4*)&WT[(size_t)(nb + nn) * KD + kb + c4] = o;
    }
}

// ---------------------------------------------------------------------------
// bf16 MFMA GEMM 128x128 (m97 structure), bf16 outputs.
// mode 1: G1 split epilogue (kvb / hqb+bq remapped). mode 2: G3, standard
// row-major bf16 C[row*512+col], rows < 64.
// ---------------------------------------------------------------------------
__global__ __launch_bounds__(256) void gemm_mfma(
    const u16* __restrict__ A, const u16* __restrict__ BT,
    u16* __restrict__ C, u16* __restrict__ C2, const float* __restrict__ bq,
    int mode)
{
    __shared__ u16 As[128 * 32];
    __shared__ u16 Bs[128 * 32];

    const int tid  = threadIdx.x;
    const int lane = tid & 63;
    const int w    = tid >> 6;
    const int wm   = (w >> 1) * 64;
    const int wn   = (w & 1) * 64;
    const int m0   = blockIdx.y * 128;
    const int n0   = blockIdx.x * 128;

    const int am0 = tid >> 2;
    const int ak0 = (tid & 3) * 8;
    const u16* ga0 = A  + (size_t)(m0 + am0) * KD + ak0;
    const u16* ga1 = ga0 + (size_t)64 * KD;
    const u16* gb0 = BT + (size_t)(n0 + am0) * KD + ak0;
    const u16* gb1 = gb0 + (size_t)64 * KD;

    f32x4 acc[4][4];
#pragma unroll
    for (int i = 0; i < 4; i++)
#pragma unroll
        for (int j = 0; j < 4; j++)
            acc[i][j] = (f32x4){0.f, 0.f, 0.f, 0.f};

    for (int kt = 0; kt < KD; kt += 32) {
        __syncthreads();
        GLLDS(ga0 + kt, &As[(size_t)w * 512]);
        GLLDS(ga1 + kt, &As[2048 + (size_t)w * 512]);
        GLLDS(gb0 + kt, &Bs[(size_t)w * 512]);
        GLLDS(gb1 + kt, &Bs[2048 + (size_t)w * 512]);
        __syncthreads();

        const int fm = lane & 15;
        const int fk = (lane >> 4) * 8;
        bf16x8 af[4], bfr[4];
#pragma unroll
        for (int i = 0; i < 4; i++)
            af[i] = *(const bf16x8*)&As[(wm + i * 16 + fm) * 32 + fk];
#pragma unroll
        for (int j = 0; j < 4; j++)
            bfr[j] = *(const bf16x8*)&Bs[(wn + j * 16 + fm) * 32 + fk];
#pragma unroll
        for (int i = 0; i < 4; i++)
#pragma unroll
            for (int j = 0; j < 4; j++)
                acc[i][j] = __builtin_amdgcn_mfma_f32_16x16x32_bf16(af[i], bfr[j], acc[i][j], 0, 0, 0);
    }

    const int fc = lane & 15;
    const int fr = (lane >> 4) * 4;
    if (mode == 1) {
        const bool iskv = (n0 < 1024);
#pragma unroll
        for (int i = 0; i < 4; i++)
#pragma unroll
            for (int rr = 0; rr < 4; rr++) {
                int row = m0 + wm + i * 16 + fr + rr;
                if (row < BB * TT) {
                    if (iskv) {
#pragma unroll
                        for (int j = 0; j < 4; j++) {
                            int col = n0 + wn + j * 16 + fc;
                            C[(size_t)row * KVN + col] = f2bf(acc[i][j][rr]);
                        }
                    } else {
                        int bb = row / TT;
                        int t  = row - bb * TT;
                        if (t >= CTX - 1) {
                            size_t orow = (size_t)(bb * QL + t - (CTX - 1));
#pragma unroll
                            for (int j = 0; j < 4; j++) {
                                int col = n0 + wn + j * 16 + fc - 1024;
                                C2[orow * HDIM + col] = f2bf(acc[i][j][rr] + bq[col]);
                            }
                        }
                    }
                }
            }
    } else {   // mode 2: hr standard row-major bf16, rows < 64
#pragma unroll
        for (int i = 0; i < 4; i++)
#pragma unroll
            for (int rr = 0; rr < 4; rr++) {
                int row = m0 + wm + i * 16 + fr + rr;
                if (row < CTX) {
#pragma unroll
                    for (int j = 0; j < 4; j++) {
                        int col = n0 + wn + j * 16 + fc;
                        C[(size_t)row * HDIM + col] = f2bf(acc[i][j][rr]);
                    }
                }
            }
    }
}

// ---------------------------------------------------------------------------
// bf16 MFMA GEMM 128(M)x64(N) tiles, fp32 C — out = attnb @ WoT (256 blocks).
// ---------------------------------------------------------------------------
__global__ __launch_bounds__(256) void gemm_n64(
    const u16* __restrict__ A, const u16* __restrict__ BT,
    float* __restrict__ C, int M, int N)
{
    __shared__ u16 As[128 * 32];
    __shared__ u16 Bs[64 * 32];

    const int tid  = threadIdx.x;
    const int lane = tid & 63;
    const int w    = tid >> 6;
    const int wm   = (w >> 1) * 64;
    const int wn   = (w & 1) * 32;
    const int m0   = blockIdx.y * 128;
    const int n0   = blockIdx.x * 64;

    const int am0 = tid >> 2;
    const int ak0 = (tid & 3) * 8;
    const u16* ga0 = A  + (size_t)(m0 + am0) * KD + ak0;
    const u16* ga1 = ga0 + (size_t)64 * KD;
    const u16* gb0 = BT + (size_t)(n0 + am0) * KD + ak0;

    f32x4 acc[4][2];
#pragma unroll
    for (int i = 0; i < 4; i++)
#pragma unroll
        for (int j = 0; j < 2; j++)
            acc[i][j] = (f32x4){0.f, 0.f, 0.f, 0.f};

    for (int kt = 0; kt < KD; kt += 32) {
        __syncthreads();
        GLLDS(ga0 + kt, &As[(size_t)w * 512]);
        GLLDS(ga1 + kt, &As[2048 + (size_t)w * 512]);
        GLLDS(gb0 + kt, &Bs[(size_t)w * 512]);
        __syncthreads();

        const int fm = lane & 15;
        const int fk = (lane >> 4) * 8;
        bf16x8 af[4], bfr[2];
#pragma unroll
        for (int i = 0; i < 4; i++)
            af[i] = *(const bf16x8*)&As[(wm + i * 16 + fm) * 32 + fk];
#pragma unroll
        for (int j = 0; j < 2; j++)
            bfr[j] = *(const bf16x8*)&Bs[(wn + j * 16 + fm) * 32 + fk];
#pragma unroll
        for (int i = 0; i < 4; i++)
#pragma unroll
            for (int j = 0; j < 2; j++)
                acc[i][j] = __builtin_amdgcn_mfma_f32_16x16x32_bf16(af[i], bfr[j], acc[i][j], 0, 0, 0);
    }

    const int fc = lane & 15;
    const int fr = (lane >> 4) * 4;
#pragma unroll
    for (int i = 0; i < 4; i++)
#pragma unroll
        for (int rr = 0; rr < 4; rr++) {
            int row = m0 + wm + i * 16 + fr + rr;
            if (row < M) {
#pragma unroll
                for (int j = 0; j < 2; j++) {
                    int col = n0 + wn + j * 16 + fc;
                    C[(size_t)row * N + col] = acc[i][j][rr];
                }
            }
        }
}

// ---------------------------------------------------------------------------
// MFMA sliding-window relative attention.
// Block = (64-q tile, h, b), 4 waves; wave w owns q rows qb=q0+w*16 .. +15.
// Phase 1 (per-wave, fragments straight from global):
//   S'[16 x 80]  = hq[16x64] @ k[t=qb..qb+80)^T   (10 MFMAs)
//   S2[16 x 64]  = hq[16x64] @ hr[64x64]^T         (8 MFMAs)
// Softmax: s[m][c] = S'[m][m+c] + S2[m][c] via LDS; weights -> banded
//   W'[64 x 128] bf16 (zero-filled; row q nonzero at t_block q..q+63).
// Phase 2: O[64x64] = W' @ V[128x64] via MFMA (16 MFMAs/wave), V staged
//   transposed vT[d][136-padded] in LDS.
// LDS: sprime 20480 (aliased by vT 17408) | s2 17408 | wband 17408 = 54 KB.
// ---------------------------------------------------------------------------
__global__ __launch_bounds__(256) void attn_mfma(
    const u16* __restrict__ kvb, const u16* __restrict__ hqb,
    const u16* __restrict__ hrb, const float* __restrict__ maskv,
    u16* __restrict__ attnb)
{
    __shared__ __align__(16) char lds[55296];
    float* sprime = (float*)lds;                 // [4][16][80]
    u16*   vTs    = (u16*)lds;                   // [64][136] (aliases sprime)
    float* s2s    = (float*)(lds + 20480);       // [4][16][68]
    u16*   wband  = (u16*)(lds + 37888);         // [64][136]

    const int q0 = blockIdx.x * 64;
    const int h  = blockIdx.y;
    const int b  = blockIdx.z;
    const int tid  = threadIdx.x;
    const int lane = tid & 63;
    const int w    = tid >> 6;
    const int qb   = q0 + w * 16;

    // zero W' band buffer (64*136 u16 = 4352 u32)
    {
        uint32_t* wz = (uint32_t*)wband;
#pragma unroll
        for (int i = 0; i < 17; i++) wz[tid + i * 256] = 0;
    }
    __syncthreads();

    const int fm = lane & 15;           // m (A) / n (B) fragment index
    const int fk = (lane >> 4) * 8;     // k quad offset

    // ---- A fragments: hq rows qb+fm ----
    const u16* hqrow = hqb + (size_t)(b * QL + qb + fm) * HDIM + h * DH + fk;
    bf16x8 afr0 = *(const bf16x8*)(hqrow);
    bf16x8 afr1 = *(const bf16x8*)(hqrow + 32);

    // ---- QK': S'[16 x 80] ----
    {
        const u16* kbase = kvb + (size_t)(b * TT + qb + fm) * KVN + h * DH + fk;
#pragma unroll
        for (int nt = 0; nt < 5; nt++) {
            bf16x8 b0 = *(const bf16x8*)(kbase + (size_t)nt * 16 * KVN);
            bf16x8 b1 = *(const bf16x8*)(kbase + (size_t)nt * 16 * KVN + 32);
            f32x4 acc = (f32x4){0.f, 0.f, 0.f, 0.f};
            acc = __builtin_amdgcn_mfma_f32_16x16x32_bf16(afr0, b0, acc, 0, 0, 0);
            acc = __builtin_amdgcn_mfma_f32_16x16x32_bf16(afr1, b1, acc, 0, 0, 0);
            const int row = (lane >> 4) * 4;
#pragma unroll
            for (int r = 0; r < 4; r++)
                sprime[w * 1280 + (row + r) * 80 + nt * 16 + fm] = acc[r];
        }
    }
    // ---- S2[16 x 64] = hq @ hr^T ----
    {
        const u16* hrbase = hrb + (size_t)fm * HDIM + h * DH + fk;
#pragma unroll
        for (int nc = 0; nc < 4; nc++) {
            bf16x8 b0 = *(const bf16x8*)(hrbase + (size_t)nc * 16 * HDIM);
            bf16x8 b1 = *(const bf16x8*)(hrbase + (size_t)nc * 16 * HDIM + 32);
            f32x4 acc = (f32x4){0.f, 0.f, 0.f, 0.f};
            acc = __builtin_amdgcn_mfma_f32_16x16x32_bf16(afr0, b0, acc, 0, 0, 0);
            acc = __builtin_amdgcn_mfma_f32_16x16x32_bf16(afr1, b1, acc, 0, 0, 0);
            const int row = (lane >> 4) * 4;
#pragma unroll
            for (int r = 0; r < 4; r++)
                s2s[w * 1088 + (row + r) * 68 + nc * 16 + fm] = acc[r];
        }
    }

    // ---- softmax (per-wave; compiler inserts lgkmcnt for LDS deps) ----
#pragma unroll 1
    for (int i = 0; i < 16; i++) {
        const int qloc = w * 16 + i;
        float s = (sprime[w * 1280 + i * 80 + i + lane] +
                   s2s[w * 1088 + i * 68 + lane]) * 0.125f;
        if (q0 == 0) {
            int t = qloc + lane;
            if (t < 63) s += maskv[b * 64 + t];
        }
        float mx = s;
#pragma unroll
        for (int off = 32; off; off >>= 1) mx = fmaxf(mx, __shfl_xor(mx, off, 64));
        float e = __expf(s - mx);
        float sum = e;
#pragma unroll
        for (int off = 32; off; off >>= 1) sum += __shfl_xor(sum, off, 64);
        wband[qloc * 136 + qloc + lane] = f2bf(e / sum);
    }
    __syncthreads();   // all waves done with sprime/s2; wband complete

    // ---- stage vT[d][t_block] (overwrites sprime region) ----
    {
        const int r0 = tid >> 4;
        const int c4 = (tid & 15) * 4;
        for (int rr = r0; rr < 127; rr += 16) {
            ushort4 vv = *(const ushort4*)&kvb[(size_t)(b * TT + q0 + rr) * KVN + HDIM + h * DH + c4];
            vTs[(c4 + 0) * 136 + rr] = vv.x;
            vTs[(c4 + 1) * 136 + rr] = vv.y;
            vTs[(c4 + 2) * 136 + rr] = vv.z;
            vTs[(c4 + 3) * 136 + rr] = vv.w;
        }
        if (tid < 64) vTs[tid * 136 + 127] = 0;   // never-staged pad column
    }
    __syncthreads();

    // ---- PV: O[16 x 64] per wave = W'[16 x 128] @ V[128 x 64] ----
    f32x4 oacc[4];
#pragma unroll
    for (int j = 0; j < 4; j++) oacc[j] = (f32x4){0.f, 0.f, 0.f, 0.f};
#pragma unroll
    for (int ks = 0; ks < 4; ks++) {
        bf16x8 wa = *(const bf16x8*)&wband[(w * 16 + fm) * 136 + ks * 32 + fk];
#pragma unroll
        for (int j = 0; j < 4; j++) {
            bf16x8 vb = *(const bf16x8*)&vTs[(j * 16 + fm) * 136 + ks * 32 + fk];
            oacc[j] = __builtin_amdgcn_mfma_f32_16x16x32_bf16(wa, vb, oacc[j], 0, 0, 0);
        }
    }
    {
        const int row = (lane >> 4) * 4;
#pragma unroll
        for (int j = 0; j < 4; j++)
#pragma unroll
            for (int r = 0; r < 4; r++)
                attnb[(size_t)(b * QL + qb + row + r) * HDIM + h * DH + j * 16 + fm] =
                    f2bf(oacc[j][r]);
    }
}

// ---------------------------------------------------------------------------
extern "C" void kernel_launch(void* const* d_in, const int* in_sizes, int n_in,
                              void* d_out, int out_size, void* d_ws, size_t ws_size,
                              hipStream_t stream)
{
    const float* x   = (const float*)d_in[0];
    const float* r   = (const float*)d_in[1];
    const float* Wkv = (const float*)d_in[2];
    const float* Wq  = (const float*)d_in[3];
    const float* bq  = (const float*)d_in[4];
    const float* Wr  = (const float*)d_in[5];
    const float* Wo  = (const float*)d_in[6];
    float* out = (float*)d_out;

    char* p = (char*)d_ws;
    u16* xb     = (u16*)p;  p += (size_t)4224 * 512 * 2;
    u16* rb     = (u16*)p;  p += (size_t)128 * 512 * 2;
    u16* WkvqT  = (u16*)p;  p += (size_t)1536 * 512 * 2;
    u16* WrT    = (u16*)p;  p += (size_t)512 * 512 * 2;
    u16* WoT    = (u16*)p;  p += (size_t)512 * 512 * 2;
    u16* kvb    = (u16*)p;  p += (size_t)4224 * 1024 * 2;
    u16* hqb    = (u16*)p;  p += (size_t)4096 * 512 * 2;
    u16* hrb    = (u16*)p;  p += (size_t)64 * 512 * 2;
    u16* attnb  = (u16*)p;  p += (size_t)4096 * 512 * 2;
    float* maskv = (float*)p;

    // 1) prep: casts, weight transposes, pad mask
    hipLaunchKernelGGL(prep_kernel, dim3(2589), dim3(256), 0, stream,
                       x, r, Wkv, Wq, Wr, Wo, xb, rb, WkvqT, WrT, WoT, maskv);
    // 2) G1: [kv|hq] = xb @ [Wkv|Wq]^T, bf16 split epilogue
    hipLaunchKernelGGL(gemm_mfma, dim3(1536 / 128, 33), dim3(256), 0, stream,
                       xb, WkvqT, kvb, hqb, bq, 1);
    // 3) G3: hr = rb @ WrT (standard row-major bf16)
    hipLaunchKernelGGL(gemm_mfma, dim3(512 / 128, 1), dim3(256), 0, stream,
                       rb, WrT, hrb, nullptr, nullptr, 2);
    // 4) MFMA attention
    hipLaunchKernelGGL(attn_mfma, dim3(QL / 64, NH, BB), dim3(256), 0, stream,
                       kvb, hqb, hrb, maskv, attnb);
    // 5) G2: out = attnb @ WoT
    hipLaunchKernelGGL(gemm_n64, dim3(512 / 64, 4096 / 128), dim3(256), 0, stream,
                       attnb, WoT, out, 4096, 512);
}

// Round 2
// 124.845 us; speedup vs baseline: 1.0700x; 1.0700x over previous
//
#include <hip/hip_runtime.h>
#include <cstdint>
#include <cstddef>

#define NH 8
#define DH 64
#define DM 512
#define CTX 64
#define BB 2
#define QL 2048
#define TT (QL + CTX - 1)   // 2111
#define HDIM 512
#define KVN 1024
#define KD 512              // K for all GEMMs

typedef unsigned short u16;
typedef __attribute__((ext_vector_type(8))) short bf16x8;   // 8 bf16 = 4 VGPRs
typedef __attribute__((ext_vector_type(4))) float f32x4;

__device__ __forceinline__ u16 f2bf(float f) {      // RNE float->bf16
    uint32_t u = __float_as_uint(f);
    u += 0x7FFF + ((u >> 16) & 1);
    return (u16)(u >> 16);
}

#define GLLDS(g, l) __builtin_amdgcn_global_load_lds( \
    (const __attribute__((address_space(1))) void*)(g), \
    (__attribute__((address_space(3))) void*)(l), 16, 0, 0)

// ---------------------------------------------------------------------------
// Fused prep: cast x,r -> bf16; transpose+cast Wkv,Wq,Wr,Wo; pad mask.
// ---------------------------------------------------------------------------
__global__ __launch_bounds__(256) void prep_kernel(
    const float* __restrict__ x, const float* __restrict__ r,
    const float* __restrict__ Wkv, const float* __restrict__ Wq,
    const float* __restrict__ Wr, const float* __restrict__ Wo,
    u16* __restrict__ xb, u16* __restrict__ rb, u16* __restrict__ WkvqT,
    u16* __restrict__ WrT, u16* __restrict__ WoT, float* __restrict__ maskv)
{
    __shared__ float tile[64][65];
    __shared__ int anyflag;
    int bid = blockIdx.x;
    const int tid = threadIdx.x;

    if (bid < 2111) {                           // x cast
        int i = bid * 256 + tid;
        float4 v = ((const float4*)x)[i];
        ushort4 o; o.x = f2bf(v.x); o.y = f2bf(v.y); o.z = f2bf(v.z); o.w = f2bf(v.w);
        ((ushort4*)xb)[i] = o;
        return;
    }
    bid -= 2111;
    if (bid < 32) {                             // r cast
        int i = bid * 256 + tid;
        float4 v = ((const float4*)r)[i];
        ushort4 o; o.x = f2bf(v.x); o.y = f2bf(v.y); o.z = f2bf(v.z); o.w = f2bf(v.w);
        ((ushort4*)rb)[i] = o;
        return;
    }
    bid -= 32;
    if (bid >= 320) {                           // pad mask
        int idx = bid - 320;
        int t = idx >> 1, b = idx & 1;
        const float* row = x + (size_t)(b * TT + t) * DM;
        bool nz = (row[tid] != 0.f) || (row[tid + 256] != 0.f);
        if (tid == 0) anyflag = 0;
        __syncthreads();
        unsigned long long bal = __ballot(nz);
        if ((tid & 63) == 0 && bal) atomicOr(&anyflag, 1);
        __syncthreads();
        if (tid == 0) maskv[b * 64 + t] = anyflag ? 0.f : -1e30f;
        return;
    }
    // weight transposes
    const float* W; u16* WT; int N; int tidx;
    if (bid < 128)      { W = Wkv; WT = WkvqT;                    N = 1024; tidx = bid; }
    else if (bid < 192) { W = Wq;  WT = WkvqT + (size_t)1024*512; N = 512;  tidx = bid - 128; }
    else if (bid < 256) { W = Wr;  WT = WrT;                      N = 512;  tidx = bid - 192; }
    else                { W = Wo;  WT = WoT;                      N = 512;  tidx = bid - 256; }
    const int tpr = N / 64;
    const int kb = (tidx / tpr) * 64, nb = (tidx % tpr) * 64;
    const int c4 = (tid & 15) * 4;
    for (int kk = tid >> 4; kk < 64; kk += 16) {
        float4 v = *(const float4*)&W[(size_t)(kb + kk) * N + nb + c4];
        tile[kk][c4 + 0] = v.x; tile[kk][c4 + 1] = v.y;
        tile[kk][c4 + 2] = v.z; tile[kk][c4 + 3] = v.w;
    }
    __syncthreads();
    for (int nn = tid >> 4; nn < 64; nn += 16) {
        ushort4 o;
        o.x = f2bf(tile[c4 + 0][nn]); o.y = f2bf(tile[c4 + 1][nn]);
        o.z = f2bf(tile[c4 + 2][nn]); o.w = f2bf(tile[c4 + 3][nn]);
        *(ushort4*)&WT[(size_t)(nb + nn) * KD + kb + c4] = o;
    }
}

// ---------------------------------------------------------------------------
// Fused G1+G3: bf16 MFMA GEMM 128x128, 2-phase prefetch (double-buffered LDS,
// stage k+1 before compute k, ONE barrier per K-step after the MFMAs).
// blocks [0,396): G1 = xb @ WkvqT^T, split epilogue (kvb / hqb+bq).
// blocks [396,400): G3 = rb @ WrT^T -> hrb (rows < 64).
// ---------------------------------------------------------------------------
__global__ __launch_bounds__(256) void gemm_fused(
    const u16* __restrict__ xb, const u16* __restrict__ WkvqT,
    u16* __restrict__ kvb, u16* __restrict__ hqb, const float* __restrict__ bq,
    const u16* __restrict__ rb, const u16* __restrict__ WrT,
    u16* __restrict__ hrb)
{
    __shared__ u16 As[2][128 * 32];
    __shared__ u16 Bs[2][128 * 32];

    const int tid  = threadIdx.x;
    const int lane = tid & 63;
    const int w    = tid >> 6;
    const int wm   = (w >> 1) * 64;
    const int wn   = (w & 1) * 64;

    const int bid = blockIdx.x;
    const bool g3 = (bid >= 396);
    const u16* A;  const u16* BT;
    int m0, n0;
    if (g3) { A = rb; BT = WrT;   m0 = 0;                n0 = (bid - 396) * 128; }
    else    { A = xb; BT = WkvqT; m0 = (bid / 12) * 128; n0 = (bid % 12) * 128; }

    const int am0 = tid >> 2;
    const int ak0 = (tid & 3) * 8;
    const u16* ga0 = A  + (size_t)(m0 + am0) * KD + ak0;
    const u16* ga1 = ga0 + (size_t)64 * KD;
    const u16* gb0 = BT + (size_t)(n0 + am0) * KD + ak0;
    const u16* gb1 = gb0 + (size_t)64 * KD;

#define STAGE_G1(buf, kt) do { \
    GLLDS(ga0 + (kt), &As[buf][(size_t)w * 512]); \
    GLLDS(ga1 + (kt), &As[buf][2048 + (size_t)w * 512]); \
    GLLDS(gb0 + (kt), &Bs[buf][(size_t)w * 512]); \
    GLLDS(gb1 + (kt), &Bs[buf][2048 + (size_t)w * 512]); \
} while (0)

    f32x4 acc[4][4];
#pragma unroll
    for (int i = 0; i < 4; i++)
#pragma unroll
        for (int j = 0; j < 4; j++)
            acc[i][j] = (f32x4){0.f, 0.f, 0.f, 0.f};

    STAGE_G1(0, 0);
    __syncthreads();           // buf0 resident

    int cur = 0;
    const int fm = lane & 15;
    const int fk = (lane >> 4) * 8;
    for (int kt = 0; kt < KD; kt += 32) {
        if (kt + 32 < KD) STAGE_G1(cur ^ 1, kt + 32);   // prefetch next tile

        bf16x8 af[4], bfr[4];
#pragma unroll
        for (int i = 0; i < 4; i++)
            af[i] = *(const bf16x8*)&As[cur][(wm + i * 16 + fm) * 32 + fk];
#pragma unroll
        for (int j = 0; j < 4; j++)
            bfr[j] = *(const bf16x8*)&Bs[cur][(wn + j * 16 + fm) * 32 + fk];
#pragma unroll
        for (int i = 0; i < 4; i++)
#pragma unroll
            for (int j = 0; j < 4; j++)
                acc[i][j] = __builtin_amdgcn_mfma_f32_16x16x32_bf16(af[i], bfr[j], acc[i][j], 0, 0, 0);

        __syncthreads();       // prefetch landed + all reads of cur done
        cur ^= 1;
    }
#undef STAGE_G1

    const int fc = lane & 15;
    const int fr = (lane >> 4) * 4;
    if (!g3) {
        const bool iskv = (n0 < 1024);
#pragma unroll
        for (int i = 0; i < 4; i++)
#pragma unroll
            for (int rr = 0; rr < 4; rr++) {
                int row = m0 + wm + i * 16 + fr + rr;
                if (row < BB * TT) {
                    if (iskv) {
#pragma unroll
                        for (int j = 0; j < 4; j++) {
                            int col = n0 + wn + j * 16 + fc;
                            kvb[(size_t)row * KVN + col] = f2bf(acc[i][j][rr]);
                        }
                    } else {
                        int bb = row / TT;
                        int t  = row - bb * TT;
                        if (t >= CTX - 1) {
                            size_t orow = (size_t)(bb * QL + t - (CTX - 1));
#pragma unroll
                            for (int j = 0; j < 4; j++) {
                                int col = n0 + wn + j * 16 + fc - 1024;
                                hqb[orow * HDIM + col] = f2bf(acc[i][j][rr] + bq[col]);
                            }
                        }
                    }
                }
            }
    } else {   // G3: hr standard row-major bf16, rows < 64
#pragma unroll
        for (int i = 0; i < 4; i++)
#pragma unroll
            for (int rr = 0; rr < 4; rr++) {
                int row = m0 + wm + i * 16 + fr + rr;
                if (row < CTX) {
#pragma unroll
                    for (int j = 0; j < 4; j++) {
                        int col = n0 + wn + j * 16 + fc;
                        hrb[(size_t)row * HDIM + col] = f2bf(acc[i][j][rr]);
                    }
                }
            }
    }
}

// ---------------------------------------------------------------------------
// bf16 MFMA GEMM 128(M)x64(N), fp32 C — out = attnb @ WoT. 2-phase prefetch.
// ---------------------------------------------------------------------------
__global__ __launch_bounds__(256) void gemm_n64(
    const u16* __restrict__ A, const u16* __restrict__ BT,
    float* __restrict__ C, int M, int N)
{
    __shared__ u16 As[2][128 * 32];
    __shared__ u16 Bs[2][64 * 32];

    const int tid  = threadIdx.x;
    const int lane = tid & 63;
    const int w    = tid >> 6;
    const int wm   = (w >> 1) * 64;
    const int wn   = (w & 1) * 32;
    const int m0   = blockIdx.y * 128;
    const int n0   = blockIdx.x * 64;

    const int am0 = tid >> 2;
    const int ak0 = (tid & 3) * 8;
    const u16* ga0 = A  + (size_t)(m0 + am0) * KD + ak0;
    const u16* ga1 = ga0 + (size_t)64 * KD;
    const u16* gb0 = BT + (size_t)(n0 + am0) * KD + ak0;

#define STAGE_G2(buf, kt) do { \
    GLLDS(ga0 + (kt), &As[buf][(size_t)w * 512]); \
    GLLDS(ga1 + (kt), &As[buf][2048 + (size_t)w * 512]); \
    GLLDS(gb0 + (kt), &Bs[buf][(size_t)w * 512]); \
} while (0)

    f32x4 acc[4][2];
#pragma unroll
    for (int i = 0; i < 4; i++)
#pragma unroll
        for (int j = 0; j < 2; j++)
            acc[i][j] = (f32x4){0.f, 0.f, 0.f, 0.f};

    STAGE_G2(0, 0);
    __syncthreads();

    int cur = 0;
    const int fm = lane & 15;
    const int fk = (lane >> 4) * 8;
    for (int kt = 0; kt < KD; kt += 32) {
        if (kt + 32 < KD) STAGE_G2(cur ^ 1, kt + 32);

        bf16x8 af[4], bfr[2];
#pragma unroll
        for (int i = 0; i < 4; i++)
            af[i] = *(const bf16x8*)&As[cur][(wm + i * 16 + fm) * 32 + fk];
#pragma unroll
        for (int j = 0; j < 2; j++)
            bfr[j] = *(const bf16x8*)&Bs[cur][(wn + j * 16 + fm) * 32 + fk];
#pragma unroll
        for (int i = 0; i < 4; i++)
#pragma unroll
            for (int j = 0; j < 2; j++)
                acc[i][j] = __builtin_amdgcn_mfma_f32_16x16x32_bf16(af[i], bfr[j], acc[i][j], 0, 0, 0);

        __syncthreads();
        cur ^= 1;
    }
#undef STAGE_G2

    const int fc = lane & 15;
    const int fr = (lane >> 4) * 4;
#pragma unroll
    for (int i = 0; i < 4; i++)
#pragma unroll
        for (int rr = 0; rr < 4; rr++) {
            int row = m0 + wm + i * 16 + fr + rr;
            if (row < M) {
#pragma unroll
                for (int j = 0; j < 2; j++) {
                    int col = n0 + wn + j * 16 + fc;
                    C[(size_t)row * N + col] = acc[i][j][rr];
                }
            }
        }
}

// ---------------------------------------------------------------------------
// MFMA sliding-window relative attention.
// Changes vs prev: (1) S2 folded into sprime via in-wave RMW (softmax does 1
// LDS read instead of 2; s2s buffer eliminated); (2) vTs no longer aliases
// sprime — V global loads issued at kernel start (stay in flight across the
// raw-barrier after wband-zero), ds_written after S2, consumed by PV after
// one __syncthreads. Removes the serial V-stage phase from the critical path.
// LDS: sprime 20480 | vTs 17408 | wband 17408 = 55296 (same total).
// ---------------------------------------------------------------------------
__global__ __launch_bounds__(256) void attn_mfma(
    const u16* __restrict__ kvb, const u16* __restrict__ hqb,
    const u16* __restrict__ hrb, const float* __restrict__ maskv,
    u16* __restrict__ attnb)
{
    __shared__ __align__(16) char lds[55296];
    float* sprime = (float*)lds;                 // [4][16][80] f32
    u16*   vTs    = (u16*)(lds + 20480);         // [64][136]
    u16*   wband  = (u16*)(lds + 37888);         // [64][136]

    const int q0 = blockIdx.x * 64;
    const int h  = blockIdx.y;
    const int b  = blockIdx.z;
    const int tid  = threadIdx.x;
    const int lane = tid & 63;
    const int w    = tid >> 6;
    const int qb   = q0 + w * 16;

    // ---- issue V loads early: 8 ushort4 per thread, in flight across QK' ----
    const int vr0 = tid >> 4;
    const int vc4 = (tid & 15) * 4;
    ushort4 vreg[8];
#pragma unroll
    for (int i = 0; i < 8; i++) {
        int rr = vr0 + i * 16;
        if (rr < 127)
            vreg[i] = *(const ushort4*)&kvb[(size_t)(b * TT + q0 + rr) * KVN + HDIM + h * DH + vc4];
        else
            vreg[i] = (ushort4){0, 0, 0, 0};     // pad column t=127 stays zero
    }

    // zero W' band buffer (64*136 u16 = 4352 u32)
    {
        uint32_t* wz = (uint32_t*)wband;
#pragma unroll
        for (int i = 0; i < 17; i++) wz[tid + i * 256] = 0;
    }
    // raw barrier with lgkm-only drain: V loads (vmcnt) stay outstanding
    asm volatile("s_waitcnt lgkmcnt(0)" ::: "memory");
    __builtin_amdgcn_s_barrier();

    const int fm = lane & 15;           // m (A) / n (B) fragment index
    const int fk = (lane >> 4) * 8;     // k quad offset

    // ---- A fragments: hq rows qb+fm ----
    const u16* hqrow = hqb + (size_t)(b * QL + qb + fm) * HDIM + h * DH + fk;
    bf16x8 afr0 = *(const bf16x8*)(hqrow);
    bf16x8 afr1 = *(const bf16x8*)(hqrow + 32);

    // ---- QK': S'[16 x 80] ----
    {
        const u16* kbase = kvb + (size_t)(b * TT + qb + fm) * KVN + h * DH + fk;
#pragma unroll
        for (int nt = 0; nt < 5; nt++) {
            bf16x8 b0 = *(const bf16x8*)(kbase + (size_t)nt * 16 * KVN);
            bf16x8 b1 = *(const bf16x8*)(kbase + (size_t)nt * 16 * KVN + 32);
            f32x4 acc = (f32x4){0.f, 0.f, 0.f, 0.f};
            acc = __builtin_amdgcn_mfma_f32_16x16x32_bf16(afr0, b0, acc, 0, 0, 0);
            acc = __builtin_amdgcn_mfma_f32_16x16x32_bf16(afr1, b1, acc, 0, 0, 0);
            const int row = (lane >> 4) * 4;
#pragma unroll
            for (int r = 0; r < 4; r++)
                sprime[w * 1280 + (row + r) * 80 + nt * 16 + fm] = acc[r];
        }
    }
    // ---- S2[16 x 64] = hq @ hr^T, folded into sprime: s[m][m+c] += S2[m][c]
    {
        const u16* hrbase = hrb + (size_t)fm * HDIM + h * DH + fk;
#pragma unroll
        for (int nc = 0; nc < 4; nc++) {
            bf16x8 b0 = *(const bf16x8*)(hrbase + (size_t)nc * 16 * HDIM);
            bf16x8 b1 = *(const bf16x8*)(hrbase + (size_t)nc * 16 * HDIM + 32);
            f32x4 acc = (f32x4){0.f, 0.f, 0.f, 0.f};
            acc = __builtin_amdgcn_mfma_f32_16x16x32_bf16(afr0, b0, acc, 0, 0, 0);
            acc = __builtin_amdgcn_mfma_f32_16x16x32_bf16(afr1, b1, acc, 0, 0, 0);
            const int row = (lane >> 4) * 4;
#pragma unroll
            for (int r = 0; r < 4; r++)
                sprime[w * 1280 + (row + r) * 81 + nc * 16 + fm] += acc[r];
        }
    }

    // ---- write V (loads have had QK'+S2 to land) ----
#pragma unroll
    for (int i = 0; i < 8; i++) {
        int rr = vr0 + i * 16;
        vTs[(vc4 + 0) * 136 + rr] = vreg[i].x;
        vTs[(vc4 + 1) * 136 + rr] = vreg[i].y;
        vTs[(vc4 + 2) * 136 + rr] = vreg[i].z;
        vTs[(vc4 + 3) * 136 + rr] = vreg[i].w;
    }

    // ---- softmax (per-wave; single fused LDS read per row) ----
#pragma unroll 1
    for (int i = 0; i < 16; i++) {
        const int qloc = w * 16 + i;
        float s = sprime[w * 1280 + i * 81 + lane] * 0.125f;
        if (q0 == 0) {
            int t = qloc + lane;
            if (t < 63) s += maskv[b * 64 + t];
        }
        float mx = s;
#pragma unroll
        for (int off = 32; off; off >>= 1) mx = fmaxf(mx, __shfl_xor(mx, off, 64));
        float e = __expf(s - mx);
        float sum = e;
#pragma unroll
        for (int off = 32; off; off >>= 1) sum += __shfl_xor(sum, off, 64);
        wband[qloc * 136 + qloc + lane] = f2bf(e / sum);
    }
    __syncthreads();   // wband + vTs complete

    // ---- PV: O[16 x 64] per wave = W'[16 x 128] @ V[128 x 64] ----
    f32x4 oacc[4];
#pragma unroll
    for (int j = 0; j < 4; j++) oacc[j] = (f32x4){0.f, 0.f, 0.f, 0.f};
#pragma unroll
    for (int ks = 0; ks < 4; ks++) {
        bf16x8 wa = *(const bf16x8*)&wband[(w * 16 + fm) * 136 + ks * 32 + fk];
#pragma unroll
        for (int j = 0; j < 4; j++) {
            bf16x8 vb = *(const bf16x8*)&vTs[(j * 16 + fm) * 136 + ks * 32 + fk];
            oacc[j] = __builtin_amdgcn_mfma_f32_16x16x32_bf16(wa, vb, oacc[j], 0, 0, 0);
        }
    }
    {
        const int row = (lane >> 4) * 4;
#pragma unroll
        for (int j = 0; j < 4; j++)
#pragma unroll
            for (int r = 0; r < 4; r++)
                attnb[(size_t)(b * QL + qb + row + r) * HDIM + h * DH + j * 16 + fm] =
                    f2bf(oacc[j][r]);
    }
}

// ---------------------------------------------------------------------------
extern "C" void kernel_launch(void* const* d_in, const int* in_sizes, int n_in,
                              void* d_out, int out_size, void* d_ws, size_t ws_size,
                              hipStream_t stream)
{
    const float* x   = (const float*)d_in[0];
    const float* r   = (const float*)d_in[1];
    const float* Wkv = (const float*)d_in[2];
    const float* Wq  = (const float*)d_in[3];
    const float* bq  = (const float*)d_in[4];
    const float* Wr  = (const float*)d_in[5];
    const float* Wo  = (const float*)d_in[6];
    float* out = (float*)d_out;

    char* p = (char*)d_ws;
    u16* xb     = (u16*)p;  p += (size_t)4224 * 512 * 2;
    u16* rb     = (u16*)p;  p += (size_t)128 * 512 * 2;
    u16* WkvqT  = (u16*)p;  p += (size_t)1536 * 512 * 2;
    u16* WrT    = (u16*)p;  p += (size_t)512 * 512 * 2;
    u16* WoT    = (u16*)p;  p += (size_t)512 * 512 * 2;
    u16* kvb    = (u16*)p;  p += (size_t)4224 * 1024 * 2;
    u16* hqb    = (u16*)p;  p += (size_t)4096 * 512 * 2;
    u16* hrb    = (u16*)p;  p += (size_t)64 * 512 * 2;
    u16* attnb  = (u16*)p;  p += (size_t)4096 * 512 * 2;
    float* maskv = (float*)p;

    // 1) prep: casts, weight transposes, pad mask
    hipLaunchKernelGGL(prep_kernel, dim3(2589), dim3(256), 0, stream,
                       x, r, Wkv, Wq, Wr, Wo, xb, rb, WkvqT, WrT, WoT, maskv);
    // 2) G1+G3 fused: [kv|hq] = xb @ [Wkv|Wq]^T (396 blocks) + hr = rb @ WrT (4)
    hipLaunchKernelGGL(gemm_fused, dim3(400), dim3(256), 0, stream,
                       xb, WkvqT, kvb, hqb, bq, rb, WrT, hrb);
    // 3) MFMA attention
    hipLaunchKernelGGL(attn_mfma, dim3(QL / 64, NH, BB), dim3(256), 0, stream,
                       kvb, hqb, hrb, maskv, attnb);
    // 4) G2: out = attnb @ WoT
    hipLaunchKernelGGL(gemm_n64, dim3(512 / 64, 4096 / 128), dim3(256), 0, stream,
                       attnb, WoT, out, 4096, 512);
}